// Round 2
// baseline (31051.953 us; speedup 1.0000x reference)
//
#include <hip/hip_runtime.h>
#include <hip/hip_bf16.h>

#define BDIM 64
#define TDIM 360
#define BT (BDIM*TDIM)        // 23040
#define CDIM 128
#define HWSZ 1024
#define SDIM 64
#define G4 512
#define KTOP 160

typedef __hip_bfloat16 bf16;

static __device__ __forceinline__ unsigned int f2bu(float x) {
    bf16 b = __float2bfloat16(x);
    unsigned short u; __builtin_memcpy(&u, &b, 2); return (unsigned int)u;
}
static __device__ __forceinline__ float b2f(bf16 x) { return __bfloat162float(x); }
static __device__ __forceinline__ float tanh_fast(float x) {
    float e = __expf(2.0f * x);
    return 1.0f - 2.0f / (e + 1.0f);
}
static __device__ __forceinline__ float sigm(float x) {
    return 1.0f / (1.0f + __expf(-x));
}

// ---- static device workspace (~87 MB) ----
__device__ float        g_ArowsF[BT * KTOP];   // [x_emb(32) | in_seq(128)] fp32
__device__ float        g_pre2[BT * G4];       // precomputed non-recurrent gate part
__device__ unsigned int g_wpack[128 * G4];     // folded recurrent weights, bf16 pairs
__device__ float        g_penc[BDIM * SDIM * 64];
__device__ float        g_hatt[BT * 256];      // [h(128) | att(128)] per (b,t)
__device__ float        g_Wao[256 * 5];
__device__ float        g_bao[5];
__device__ float        g_bias[G4];
__device__ float        g_c0[G4];

// ---- A1: build [x_emb | gathered feature] rows (f32 in, f32 out) ----
__global__ void kA1(const float* __restrict__ tok, const float* __restrict__ feat,
                    const float* __restrict__ Wemb, const float* __restrict__ bemb) {
    int row  = blockIdx.x * 4 + (threadIdx.x >> 6);
    int lane = threadIdx.x & 63;
    const float* tp = tok + (size_t)row * 4;
    float t0 = tp[0], t1 = tp[1], t2 = tp[2], t3 = tp[3];
    int b = row / TDIM;
    int x = (int)(t0 * 100.0f);
    int y = (int)(t1 * 100.0f);
    x = min(max(x, 0), 31);
    y = min(max(y, 0), 31);
    int idx = y * 32 + x;                       // y*H + x, H=32
    float* out = g_ArowsF + (size_t)row * KTOP;
    if (lane < 32) {
        float e = t0 * Wemb[lane] + t1 * Wemb[32 + lane] +
                  t2 * Wemb[64 + lane] + t3 * Wemb[96 + lane] + bemb[lane];
        out[lane] = e;
    }
    const float* fb = feat + (size_t)b * CDIM * HWSZ + idx;
    out[32 + lane]      = fb[(size_t)lane * HWSZ];
    out[32 + 64 + lane] = fb[(size_t)(64 + lane) * HWSZ];
}

// ---- A2a: fold recurrent weights: Wrec[kk,n] = (kk<128 ? W_hh[kk,n] : 0) + sum_j W_aap[kk,j]*W_ih[160+j,n]
__global__ void kA2a(const float* __restrict__ Wih, const float* __restrict__ Whh,
                     const float* __restrict__ Waap) {
    __shared__ float sa0[128], sa1[128];
    int p = blockIdx.x, n = threadIdx.x;
    int r0 = 2 * p, r1 = 2 * p + 1;
    if (n < 128)            sa0[n]        = Waap[r0 * 128 + n];
    else if (n < 256)       sa1[n - 128]  = Waap[r1 * 128 + (n - 128)];
    __syncthreads();
    float acc0 = (r0 < 128) ? Whh[r0 * G4 + n] : 0.0f;
    float acc1 = (r1 < 128) ? Whh[r1 * G4 + n] : 0.0f;
    for (int j = 0; j < 128; ++j) {
        float wi = Wih[(160 + j) * G4 + n];
        acc0 += sa0[j] * wi;
        acc1 += sa1[j] * wi;
    }
    g_wpack[p * G4 + n] = f2bu(acc0) | (f2bu(acc1) << 16);
}

// ---- A2c: bias vectors, c0 = b_aap@Wi2, Wao = W_aap@W_out, bao ----
__global__ void kA2c(const float* __restrict__ bih, const float* __restrict__ bhh,
                     const float* __restrict__ Wih, const float* __restrict__ Waap,
                     const float* __restrict__ baap, const float* __restrict__ Wout,
                     const float* __restrict__ bout) {
    __shared__ float sb[128];
    int n = threadIdx.x;
    if (n < 128) sb[n] = baap[n];
    __syncthreads();
    g_bias[n] = bih[n] + bhh[n];
    float c0 = 0.0f;
    for (int j = 0; j < 128; ++j) c0 += sb[j] * Wih[(160 + j) * G4 + n];
    g_c0[n] = c0;
    if (n < 256) {
        for (int o = 0; o < 5; ++o) {
            float acc = 0.0f;
            for (int j = 0; j < 128; ++j) acc += Waap[n * 128 + j] * Wout[j * 5 + o];
            g_Wao[n * 5 + o] = acc;
        }
    }
    if (n == 0) {
        for (int o = 0; o < 5; ++o) {
            float acc = bout[o];
            for (int j = 0; j < 128; ++j) acc += sb[j] * Wout[j * 5 + o];
            g_bao[o] = acc;
        }
    }
}

// ---- A2d: p_enc[b,s,a] = sum_d FH[b,d,s]*W_encproj[d,a] + b_encproj[a] ----
__global__ void kA2d(const float* __restrict__ FH, const float* __restrict__ Wep,
                     const float* __restrict__ bep) {
    __shared__ float sfh[128 * 64];
    int b = blockIdx.x, tid = threadIdx.x;
    for (int i = tid; i < 128 * 64; i += 256) sfh[i] = FH[(size_t)b * 128 * 64 + i];
    __syncthreads();
    int a = tid & 63, sg = tid >> 6;
    float bias = bep[a];
    float acc[16];
#pragma unroll
    for (int i = 0; i < 16; ++i) acc[i] = bias;
    for (int d = 0; d < 128; ++d) {
        float wa = Wep[d * 64 + a];
#pragma unroll
        for (int i = 0; i < 16; ++i) acc[i] += sfh[d * 64 + sg * 16 + i] * wa;
    }
    for (int i = 0; i < 16; ++i)
        g_penc[((size_t)b * 64 + sg * 16 + i) * 64 + a] = acc[i];
}

// ---- B: pre2 = Arows @ W_ih[0:160]  ([23040,160]@[160,512], fp32 VALU, weights in regs) ----
__global__ void __launch_bounds__(512) kB(const float* __restrict__ Wih) {
    int n = threadIdx.x;
    int m0 = blockIdx.x * 16;
    float wcol[KTOP];
#pragma unroll
    for (int k = 0; k < KTOP; ++k) wcol[k] = Wih[k * G4 + n];
#pragma unroll 1
    for (int r = 0; r < 16; ++r) {
        const float4* rp = (const float4*)(g_ArowsF + (size_t)(m0 + r) * KTOP);
        float a0 = 0.f, a1 = 0.f, a2 = 0.f, a3 = 0.f;
#pragma unroll
        for (int q = 0; q < 40; ++q) {
            float4 v = rp[q];
            a0 += wcol[4 * q + 0] * v.x;
            a1 += wcol[4 * q + 1] * v.y;
            a2 += wcol[4 * q + 2] * v.z;
            a3 += wcol[4 * q + 3] * v.w;
        }
        g_pre2[(size_t)(m0 + r) * G4 + n] = (a0 + a1) + (a2 + a3);
    }
}

// ---- C: the sequential recurrence, one block per batch element ----
__global__ void __launch_bounds__(512) kC(const float* __restrict__ FH,
                                          const float* __restrict__ W2a,
                                          const float* __restrict__ Walpha,
                                          const float* __restrict__ balpha,
                                          const float* __restrict__ bh2a) {
    __shared__ __align__(16) float s_val[256];   // [h(128) | att(128)]
    __shared__ float s_c[128];
    __shared__ float s_gates[512];
    __shared__ float s_atth[64];
    __shared__ float s_scores[64];
    __shared__ float s_wgt[64];
    __shared__ float s_red[8 * 64];
    __shared__ float s_red4[4 * 128];
    __shared__ float s_bias[512];
    __shared__ float s_c0[512];
    __shared__ float s_walpha[64];
    __shared__ float s_bh2a[64];
    __shared__ float s_penc[64 * 65];            // padded stride 65
    __shared__ bf16  s_encp[128 * 70];           // enc[d][s], padded stride 70
    __shared__ bf16  s_w2a[128 * 64];

    int tid = threadIdx.x;
    int b = blockIdx.x;

    unsigned int wreg[128];
#pragma unroll
    for (int p = 0; p < 128; ++p) wreg[p] = g_wpack[p * G4 + tid];

    if (tid < 256) s_val[tid] = 0.0f;
    if (tid < 128) s_c[tid] = 0.0f;
    s_bias[tid] = g_bias[tid];
    s_c0[tid]   = g_c0[tid];
    if (tid < 64) { s_walpha[tid] = Walpha[tid]; s_bh2a[tid] = bh2a[tid]; }
    for (int i = tid; i < 64 * 64; i += 512) {
        int s = i >> 6, a = i & 63;
        s_penc[s * 65 + a] = g_penc[((size_t)b * 64 + s) * 64 + a];
    }
    for (int i = tid; i < 128 * 64; i += 512) {
        int d = i >> 6, s = i & 63;
        s_encp[d * 70 + s] = __float2bfloat16(FH[(size_t)b * 128 * 64 + i]);
        s_w2a[i] = __float2bfloat16(W2a[i]);
    }
    float bal = balpha[0];

    const float* pre2p = g_pre2 + (size_t)b * TDIM * G4 + tid;
    float* hattp = g_hatt + (size_t)b * TDIM * 256;

    for (int t = 0; t < TDIM; ++t) {
        __syncthreads();                       // s_val (h_{t-1}, att_{t-1}) ready
        float pre2v = pre2p[(size_t)t * G4];
        float acc0 = 0.f, acc1 = 0.f;
        const float4* vals = (const float4*)s_val;
#pragma unroll
        for (int q = 0; q < 64; ++q) {
            float4 v = vals[q];
            unsigned int w0 = wreg[2 * q], w1 = wreg[2 * q + 1];
            acc0 += __uint_as_float(w0 << 16)          * v.x;
            acc1 += __uint_as_float(w0 & 0xffff0000u)  * v.y;
            acc0 += __uint_as_float(w1 << 16)          * v.z;
            acc1 += __uint_as_float(w1 & 0xffff0000u)  * v.w;
        }
        float g = acc0 + acc1 + pre2v + s_bias[tid] + (t ? s_c0[tid] : 0.0f);
        s_gates[tid] = g;
        __syncthreads();
        // LSTM pointwise (gate order i,f,g,o)
        if (tid < 128) {
            float si = sigm(s_gates[tid]);
            float sf = sigm(s_gates[128 + tid]);
            float tg = tanh_fast(s_gates[256 + tid]);
            float so = sigm(s_gates[384 + tid]);
            float c = sf * s_c[tid] + si * tg;
            s_c[tid] = c;
            float h = so * tanh_fast(c);
            s_val[tid] = h;
            hattp[(size_t)t * 256 + tid] = h;
        }
        __syncthreads();
        // att_h = h @ W_h2att
        {
            int a = tid & 63, sub = tid >> 6;
            float acc = 0.f;
#pragma unroll
            for (int j = 0; j < 16; ++j) {
                int k = sub * 16 + j;
                acc += s_val[k] * b2f(s_w2a[k * 64 + a]);
            }
            s_red[sub * 64 + a] = acc;
        }
        __syncthreads();
        if (tid < 64) {
            float acc = s_bh2a[tid];
#pragma unroll
            for (int sub = 0; sub < 8; ++sub) acc += s_red[sub * 64 + tid];
            s_atth[tid] = acc;
        }
        __syncthreads();
        // scores[s] = sum_a tanh(p_enc + att_h) * W_alpha
        {
            int ss = tid >> 3, sub = tid & 7;
            float acc = 0.f;
#pragma unroll
            for (int j = 0; j < 8; ++j) {
                int a = sub * 8 + j;
                float xv = s_penc[ss * 65 + a] + s_atth[a];
                acc += tanh_fast(xv) * s_walpha[a];
            }
            acc += __shfl_xor(acc, 1);
            acc += __shfl_xor(acc, 2);
            acc += __shfl_xor(acc, 4);
            if (sub == 0) s_scores[ss] = acc + bal;
        }
        __syncthreads();
        if (tid < 64) {
            float v = s_scores[tid];
            float m = v;
#pragma unroll
            for (int off = 32; off > 0; off >>= 1) m = fmaxf(m, __shfl_xor(m, off));
            float e = __expf(v - m);
            float sum = e;
#pragma unroll
            for (int off = 32; off > 0; off >>= 1) sum += __shfl_xor(sum, off);
            s_wgt[tid] = e / sum;
        }
        __syncthreads();
        // att_res[d] = sum_s wgt[s] * enc[s,d]
        {
            int d = tid & 127, sc = tid >> 7;
            float acc = 0.f;
#pragma unroll
            for (int j = 0; j < 16; ++j) {
                int s5 = sc * 16 + j;
                acc += s_wgt[s5] * b2f(s_encp[d * 70 + s5]);
            }
            s_red4[sc * 128 + d] = acc;
        }
        __syncthreads();
        if (tid < 128) {
            float att = s_red4[tid] + s_red4[128 + tid] + s_red4[256 + tid] + s_red4[384 + tid];
            s_val[128 + tid] = att;
            hattp[(size_t)t * 256 + 128 + tid] = att;
        }
        // loop-top barrier covers s_val reuse
    }
}

// ---- D: final out = [h|att] @ (W_aap@W_out) + bao, f32 output ----
__global__ void kD(float* __restrict__ out) {
    int r = blockIdx.x, lane = threadIdx.x;
    const float4* hv = (const float4*)(g_hatt + (size_t)r * 256);
    float4 v = hv[lane];
    int k0 = lane * 4;
    float acc[5];
#pragma unroll
    for (int o = 0; o < 5; ++o)
        acc[o] = v.x * g_Wao[(k0 + 0) * 5 + o] + v.y * g_Wao[(k0 + 1) * 5 + o] +
                 v.z * g_Wao[(k0 + 2) * 5 + o] + v.w * g_Wao[(k0 + 3) * 5 + o];
#pragma unroll
    for (int off = 32; off > 0; off >>= 1) {
#pragma unroll
        for (int o = 0; o < 5; ++o) acc[o] += __shfl_xor(acc[o], off);
    }
    if (lane == 0) {
#pragma unroll
        for (int o = 0; o < 5; ++o) out[(size_t)r * 5 + o] = acc[o] + g_bao[o];
    }
}

extern "C" void kernel_launch(void* const* d_in, const int* in_sizes, int n_in,
                              void* d_out, int out_size, void* d_ws, size_t ws_size,
                              hipStream_t stream) {
    (void)in_sizes; (void)n_in; (void)d_ws; (void)ws_size; (void)out_size;
    const float* tok  = (const float*)d_in[0];
    const float* feat = (const float*)d_in[1];
    const float* FH   = (const float*)d_in[2];
    const float* Wemb = (const float*)d_in[3];
    const float* bemb = (const float*)d_in[4];
    const float* Wih  = (const float*)d_in[5];
    const float* bih  = (const float*)d_in[6];
    const float* Whh  = (const float*)d_in[7];
    const float* bhh  = (const float*)d_in[8];
    const float* W2a  = (const float*)d_in[9];
    const float* bh2a = (const float*)d_in[10];
    const float* Wal  = (const float*)d_in[11];
    const float* bal  = (const float*)d_in[12];
    const float* Wep  = (const float*)d_in[13];
    const float* bep  = (const float*)d_in[14];
    const float* Waap = (const float*)d_in[15];
    const float* baap = (const float*)d_in[16];
    const float* Wout = (const float*)d_in[17];
    const float* bout = (const float*)d_in[18];
    float* out = (float*)d_out;

    kA1<<<dim3(BT / 4), dim3(256), 0, stream>>>(tok, feat, Wemb, bemb);
    kA2a<<<dim3(128), dim3(512), 0, stream>>>(Wih, Whh, Waap);
    kA2c<<<dim3(1), dim3(512), 0, stream>>>(bih, bhh, Wih, Waap, baap, Wout, bout);
    kA2d<<<dim3(64), dim3(256), 0, stream>>>(FH, Wep, bep);
    kB<<<dim3(BT / 16), dim3(512), 0, stream>>>(Wih);
    kC<<<dim3(64), dim3(512), 0, stream>>>(FH, W2a, Wal, bal, bh2a);
    kD<<<dim3(BT), dim3(64), 0, stream>>>(out);
}

// Round 3
// 31039.130 us; speedup vs baseline: 1.0004x; 1.0004x over previous
//
#include <hip/hip_runtime.h>
#include <hip/hip_bf16.h>

#define BDIM 64
#define TDIM 360
#define BT (BDIM*TDIM)        // 23040
#define CDIM 128
#define HWSZ 1024
#define SDIM 64
#define G4 512
#define KTOP 160

typedef __hip_bfloat16 bf16;

static __device__ __forceinline__ unsigned int f2bu(float x) {
    bf16 b = __float2bfloat16(x);
    unsigned short u; __builtin_memcpy(&u, &b, 2); return (unsigned int)u;
}
static __device__ __forceinline__ float b2f(bf16 x) { return __bfloat162float(x); }
static __device__ __forceinline__ float tanh_fast(float x) {
    float e = __expf(2.0f * x);
    return 1.0f - 2.0f / (e + 1.0f);
}
static __device__ __forceinline__ float sigm(float x) {
    return 1.0f / (1.0f + __expf(-x));
}

// ---- static device workspace (~87 MB) ----
__device__ float        g_ArowsF[BT * KTOP];   // [x_emb(32) | in_seq(128)] fp32
__device__ float        g_pre2[BT * G4];       // precomputed non-recurrent gate part
__device__ unsigned int g_wpack[128 * G4];     // folded recurrent weights, bf16 pairs
__device__ float        g_penc[BDIM * SDIM * 64];
__device__ float        g_hatt[BT * 256];      // [h(128) | att(128)] per (b,t)
__device__ float        g_Wao[256 * 5];
__device__ float        g_bao[5];
__device__ float        g_bias[G4];
__device__ float        g_c0[G4];

// ---- A1: build [x_emb | gathered feature] rows (f32 in, f32 out) ----
__global__ void kA1(const float* __restrict__ tok, const float* __restrict__ feat,
                    const float* __restrict__ Wemb, const float* __restrict__ bemb) {
    int row  = blockIdx.x * 4 + (threadIdx.x >> 6);
    int lane = threadIdx.x & 63;
    const float* tp = tok + (size_t)row * 4;
    float t0 = tp[0], t1 = tp[1], t2 = tp[2], t3 = tp[3];
    int b = row / TDIM;
    int x = (int)(t0 * 100.0f);
    int y = (int)(t1 * 100.0f);
    x = min(max(x, 0), 31);
    y = min(max(y, 0), 31);
    int idx = y * 32 + x;                       // y*H + x, H=32
    float* out = g_ArowsF + (size_t)row * KTOP;
    if (lane < 32) {
        float e = t0 * Wemb[lane] + t1 * Wemb[32 + lane] +
                  t2 * Wemb[64 + lane] + t3 * Wemb[96 + lane] + bemb[lane];
        out[lane] = e;
    }
    const float* fb = feat + (size_t)b * CDIM * HWSZ + idx;
    out[32 + lane]      = fb[(size_t)lane * HWSZ];
    out[32 + 64 + lane] = fb[(size_t)(64 + lane) * HWSZ];
}

// ---- A2a: fold recurrent weights: Wrec[kk,n] = (kk<128 ? W_hh[kk,n] : 0) + sum_j W_aap[kk,j]*W_ih[160+j,n]
__global__ void kA2a(const float* __restrict__ Wih, const float* __restrict__ Whh,
                     const float* __restrict__ Waap) {
    __shared__ float sa0[128], sa1[128];
    int p = blockIdx.x, n = threadIdx.x;
    int r0 = 2 * p, r1 = 2 * p + 1;
    if (n < 128)            sa0[n]        = Waap[r0 * 128 + n];
    else if (n < 256)       sa1[n - 128]  = Waap[r1 * 128 + (n - 128)];
    __syncthreads();
    float acc0 = (r0 < 128) ? Whh[r0 * G4 + n] : 0.0f;
    float acc1 = (r1 < 128) ? Whh[r1 * G4 + n] : 0.0f;
    for (int j = 0; j < 128; ++j) {
        float wi = Wih[(160 + j) * G4 + n];
        acc0 += sa0[j] * wi;
        acc1 += sa1[j] * wi;
    }
    g_wpack[p * G4 + n] = f2bu(acc0) | (f2bu(acc1) << 16);
}

// ---- A2c: bias vectors, c0 = b_aap@Wi2, Wao = W_aap@W_out, bao ----
__global__ void kA2c(const float* __restrict__ bih, const float* __restrict__ bhh,
                     const float* __restrict__ Wih, const float* __restrict__ Waap,
                     const float* __restrict__ baap, const float* __restrict__ Wout,
                     const float* __restrict__ bout) {
    __shared__ float sb[128];
    int n = threadIdx.x;
    if (n < 128) sb[n] = baap[n];
    __syncthreads();
    g_bias[n] = bih[n] + bhh[n];
    float c0 = 0.0f;
    for (int j = 0; j < 128; ++j) c0 += sb[j] * Wih[(160 + j) * G4 + n];
    g_c0[n] = c0;
    if (n < 256) {
        for (int o = 0; o < 5; ++o) {
            float acc = 0.0f;
            for (int j = 0; j < 128; ++j) acc += Waap[n * 128 + j] * Wout[j * 5 + o];
            g_Wao[n * 5 + o] = acc;
        }
    }
    if (n == 0) {
        for (int o = 0; o < 5; ++o) {
            float acc = bout[o];
            for (int j = 0; j < 128; ++j) acc += sb[j] * Wout[j * 5 + o];
            g_bao[o] = acc;
        }
    }
}

// ---- A2d: p_enc[b,s,a] = sum_d FH[b,d,s]*W_encproj[d,a] + b_encproj[a] ----
__global__ void kA2d(const float* __restrict__ FH, const float* __restrict__ Wep,
                     const float* __restrict__ bep) {
    __shared__ float sfh[128 * 64];
    int b = blockIdx.x, tid = threadIdx.x;
    for (int i = tid; i < 128 * 64; i += 256) sfh[i] = FH[(size_t)b * 128 * 64 + i];
    __syncthreads();
    int a = tid & 63, sg = tid >> 6;
    float bias = bep[a];
    float acc[16];
#pragma unroll
    for (int i = 0; i < 16; ++i) acc[i] = bias;
    for (int d = 0; d < 128; ++d) {
        float wa = Wep[d * 64 + a];
#pragma unroll
        for (int i = 0; i < 16; ++i) acc[i] += sfh[d * 64 + sg * 16 + i] * wa;
    }
    for (int i = 0; i < 16; ++i)
        g_penc[((size_t)b * 64 + sg * 16 + i) * 64 + a] = acc[i];
}

// ---- B: pre2 = Arows @ W_ih[0:160]  ([23040,160]@[160,512], fp32 VALU, weights in regs)
// __launch_bounds__(512, 2): 256-VGPR cap so wcol[160] stays in registers (128-cap spills it).
__global__ void __launch_bounds__(512, 2) kB(const float* __restrict__ Wih) {
    int n = threadIdx.x;
    int m0 = blockIdx.x * 16;
    float wcol[KTOP];
#pragma unroll
    for (int k = 0; k < KTOP; ++k) wcol[k] = Wih[k * G4 + n];
#pragma unroll 1
    for (int r = 0; r < 16; ++r) {
        const float4* rp = (const float4*)(g_ArowsF + (size_t)(m0 + r) * KTOP);
        float a0 = 0.f, a1 = 0.f, a2 = 0.f, a3 = 0.f;
#pragma unroll
        for (int q = 0; q < 40; ++q) {
            float4 v = rp[q];
            a0 += wcol[4 * q + 0] * v.x;
            a1 += wcol[4 * q + 1] * v.y;
            a2 += wcol[4 * q + 2] * v.z;
            a3 += wcol[4 * q + 3] * v.w;
        }
        g_pre2[(size_t)(m0 + r) * G4 + n] = (a0 + a1) + (a2 + a3);
    }
}

// ---- C: the sequential recurrence, one block per batch element ----
// __launch_bounds__(512, 2): 2 waves/SIMD -> 256-VGPR cap; wreg[128] + temps (~200) fit.
// Round-2 default capped at 128 VGPRs and spilled all of wreg -> 6.6 GB scratch traffic.
__global__ void __launch_bounds__(512, 2) kC(const float* __restrict__ FH,
                                             const float* __restrict__ W2a,
                                             const float* __restrict__ Walpha,
                                             const float* __restrict__ balpha,
                                             const float* __restrict__ bh2a) {
    __shared__ __align__(16) float s_val[256];   // [h(128) | att(128)]
    __shared__ float s_c[128];
    __shared__ float s_gates[512];
    __shared__ float s_atth[64];
    __shared__ float s_scores[64];
    __shared__ float s_wgt[64];
    __shared__ float s_red[8 * 64];
    __shared__ float s_red4[4 * 128];
    __shared__ float s_bias[512];
    __shared__ float s_c0[512];
    __shared__ float s_walpha[64];
    __shared__ float s_bh2a[64];
    __shared__ float s_penc[64 * 65];            // padded stride 65
    __shared__ bf16  s_encp[128 * 70];           // enc[d][s], padded stride 70
    __shared__ bf16  s_w2a[128 * 64];

    int tid = threadIdx.x;
    int b = blockIdx.x;

    unsigned int wreg[128];
#pragma unroll
    for (int p = 0; p < 128; ++p) wreg[p] = g_wpack[p * G4 + tid];

    if (tid < 256) s_val[tid] = 0.0f;
    if (tid < 128) s_c[tid] = 0.0f;
    s_bias[tid] = g_bias[tid];
    s_c0[tid]   = g_c0[tid];
    if (tid < 64) { s_walpha[tid] = Walpha[tid]; s_bh2a[tid] = bh2a[tid]; }
    for (int i = tid; i < 64 * 64; i += 512) {
        int s = i >> 6, a = i & 63;
        s_penc[s * 65 + a] = g_penc[((size_t)b * 64 + s) * 64 + a];
    }
    for (int i = tid; i < 128 * 64; i += 512) {
        int d = i >> 6, s = i & 63;
        s_encp[d * 70 + s] = __float2bfloat16(FH[(size_t)b * 128 * 64 + i]);
        s_w2a[i] = __float2bfloat16(W2a[i]);
    }
    float bal = balpha[0];

    const float* pre2p = g_pre2 + (size_t)b * TDIM * G4 + tid;
    float* hattp = g_hatt + (size_t)b * TDIM * 256;

    for (int t = 0; t < TDIM; ++t) {
        __syncthreads();                       // s_val (h_{t-1}, att_{t-1}) ready
        float pre2v = pre2p[(size_t)t * G4];
        float acc0 = 0.f, acc1 = 0.f;
        const float4* vals = (const float4*)s_val;
#pragma unroll
        for (int q = 0; q < 64; ++q) {
            float4 v = vals[q];
            unsigned int w0 = wreg[2 * q], w1 = wreg[2 * q + 1];
            acc0 += __uint_as_float(w0 << 16)          * v.x;
            acc1 += __uint_as_float(w0 & 0xffff0000u)  * v.y;
            acc0 += __uint_as_float(w1 << 16)          * v.z;
            acc1 += __uint_as_float(w1 & 0xffff0000u)  * v.w;
        }
        float g = acc0 + acc1 + pre2v + s_bias[tid] + (t ? s_c0[tid] : 0.0f);
        s_gates[tid] = g;
        __syncthreads();
        // LSTM pointwise (gate order i,f,g,o)
        if (tid < 128) {
            float si = sigm(s_gates[tid]);
            float sf = sigm(s_gates[128 + tid]);
            float tg = tanh_fast(s_gates[256 + tid]);
            float so = sigm(s_gates[384 + tid]);
            float c = sf * s_c[tid] + si * tg;
            s_c[tid] = c;
            float h = so * tanh_fast(c);
            s_val[tid] = h;
            hattp[(size_t)t * 256 + tid] = h;
        }
        __syncthreads();
        // att_h = h @ W_h2att
        {
            int a = tid & 63, sub = tid >> 6;
            float acc = 0.f;
#pragma unroll
            for (int j = 0; j < 16; ++j) {
                int k = sub * 16 + j;
                acc += s_val[k] * b2f(s_w2a[k * 64 + a]);
            }
            s_red[sub * 64 + a] = acc;
        }
        __syncthreads();
        if (tid < 64) {
            float acc = s_bh2a[tid];
#pragma unroll
            for (int sub = 0; sub < 8; ++sub) acc += s_red[sub * 64 + tid];
            s_atth[tid] = acc;
        }
        __syncthreads();
        // scores[s] = sum_a tanh(p_enc + att_h) * W_alpha
        {
            int ss = tid >> 3, sub = tid & 7;
            float acc = 0.f;
#pragma unroll
            for (int j = 0; j < 8; ++j) {
                int a = sub * 8 + j;
                float xv = s_penc[ss * 65 + a] + s_atth[a];
                acc += tanh_fast(xv) * s_walpha[a];
            }
            acc += __shfl_xor(acc, 1);
            acc += __shfl_xor(acc, 2);
            acc += __shfl_xor(acc, 4);
            if (sub == 0) s_scores[ss] = acc + bal;
        }
        __syncthreads();
        if (tid < 64) {
            float v = s_scores[tid];
            float m = v;
#pragma unroll
            for (int off = 32; off > 0; off >>= 1) m = fmaxf(m, __shfl_xor(m, off));
            float e = __expf(v - m);
            float sum = e;
#pragma unroll
            for (int off = 32; off > 0; off >>= 1) sum += __shfl_xor(sum, off);
            s_wgt[tid] = e / sum;
        }
        __syncthreads();
        // att_res[d] = sum_s wgt[s] * enc[s,d]
        {
            int d = tid & 127, sc = tid >> 7;
            float acc = 0.f;
#pragma unroll
            for (int j = 0; j < 16; ++j) {
                int s5 = sc * 16 + j;
                acc += s_wgt[s5] * b2f(s_encp[d * 70 + s5]);
            }
            s_red4[sc * 128 + d] = acc;
        }
        __syncthreads();
        if (tid < 128) {
            float att = s_red4[tid] + s_red4[128 + tid] + s_red4[256 + tid] + s_red4[384 + tid];
            s_val[128 + tid] = att;
            hattp[(size_t)t * 256 + 128 + tid] = att;
        }
        // loop-top barrier covers s_val reuse
    }
}

// ---- D: final out = [h|att] @ (W_aap@W_out) + bao, f32 output ----
__global__ void kD(float* __restrict__ out) {
    int r = blockIdx.x, lane = threadIdx.x;
    const float4* hv = (const float4*)(g_hatt + (size_t)r * 256);
    float4 v = hv[lane];
    int k0 = lane * 4;
    float acc[5];
#pragma unroll
    for (int o = 0; o < 5; ++o)
        acc[o] = v.x * g_Wao[(k0 + 0) * 5 + o] + v.y * g_Wao[(k0 + 1) * 5 + o] +
                 v.z * g_Wao[(k0 + 2) * 5 + o] + v.w * g_Wao[(k0 + 3) * 5 + o];
#pragma unroll
    for (int off = 32; off > 0; off >>= 1) {
#pragma unroll
        for (int o = 0; o < 5; ++o) acc[o] += __shfl_xor(acc[o], off);
    }
    if (lane == 0) {
#pragma unroll
        for (int o = 0; o < 5; ++o) out[(size_t)r * 5 + o] = acc[o] + g_bao[o];
    }
}

extern "C" void kernel_launch(void* const* d_in, const int* in_sizes, int n_in,
                              void* d_out, int out_size, void* d_ws, size_t ws_size,
                              hipStream_t stream) {
    (void)in_sizes; (void)n_in; (void)d_ws; (void)ws_size; (void)out_size;
    const float* tok  = (const float*)d_in[0];
    const float* feat = (const float*)d_in[1];
    const float* FH   = (const float*)d_in[2];
    const float* Wemb = (const float*)d_in[3];
    const float* bemb = (const float*)d_in[4];
    const float* Wih  = (const float*)d_in[5];
    const float* bih  = (const float*)d_in[6];
    const float* Whh  = (const float*)d_in[7];
    const float* bhh  = (const float*)d_in[8];
    const float* W2a  = (const float*)d_in[9];
    const float* bh2a = (const float*)d_in[10];
    const float* Wal  = (const float*)d_in[11];
    const float* bal  = (const float*)d_in[12];
    const float* Wep  = (const float*)d_in[13];
    const float* bep  = (const float*)d_in[14];
    const float* Waap = (const float*)d_in[15];
    const float* baap = (const float*)d_in[16];
    const float* Wout = (const float*)d_in[17];
    const float* bout = (const float*)d_in[18];
    float* out = (float*)d_out;

    kA1<<<dim3(BT / 4), dim3(256), 0, stream>>>(tok, feat, Wemb, bemb);
    kA2a<<<dim3(128), dim3(512), 0, stream>>>(Wih, Whh, Waap);
    kA2c<<<dim3(1), dim3(512), 0, stream>>>(bih, bhh, Wih, Waap, baap, Wout, bout);
    kA2d<<<dim3(64), dim3(256), 0, stream>>>(FH, Wep, bep);
    kB<<<dim3(BT / 16), dim3(512), 0, stream>>>(Wih);
    kC<<<dim3(64), dim3(512), 0, stream>>>(FH, W2a, Wal, bal, bh2a);
    kD<<<dim3(BT), dim3(64), 0, stream>>>(out);
}

// Round 4
// 3624.290 us; speedup vs baseline: 8.5677x; 8.5642x over previous
//
#include <hip/hip_runtime.h>
#include <hip/hip_bf16.h>

#define BDIM 64
#define TDIM 360
#define BT (BDIM*TDIM)        // 23040
#define CDIM 128
#define HWSZ 1024
#define SDIM 64
#define G4 512
#define KTOP 160

typedef __hip_bfloat16 bf16;

static __device__ __forceinline__ unsigned int f2bu(float x) {
    bf16 b = __float2bfloat16(x);
    unsigned short u; __builtin_memcpy(&u, &b, 2); return (unsigned int)u;
}
static __device__ __forceinline__ float b2f(bf16 x) { return __bfloat162float(x); }
static __device__ __forceinline__ float tanh_fast(float x) {
    float e = __expf(2.0f * x);
    return 1.0f - 2.0f / (e + 1.0f);
}
static __device__ __forceinline__ float sigm(float x) {
    return 1.0f / (1.0f + __expf(-x));
}

// ---- static device workspace (~87 MB) ----
__device__ float        g_ArowsF[BT * KTOP];   // [x_emb(32) | in_seq(128)] fp32
__device__ float        g_pre2[BT * G4];       // precomputed non-recurrent gate part
__device__ unsigned int g_wpack[128 * G4];     // folded recurrent weights, bf16 pairs
__device__ float        g_penc[BDIM * SDIM * 64];
__device__ float        g_hatt[BT * 256];      // [h(128) | att(128)] per (b,t)
__device__ float        g_Wao[256 * 5];
__device__ float        g_bao[5];
__device__ float        g_bias[G4];
__device__ float        g_c0[G4];

// ---- A1: build [x_emb | gathered feature] rows (f32 in, f32 out) ----
__global__ void kA1(const float* __restrict__ tok, const float* __restrict__ feat,
                    const float* __restrict__ Wemb, const float* __restrict__ bemb) {
    int row  = blockIdx.x * 4 + (threadIdx.x >> 6);
    int lane = threadIdx.x & 63;
    const float* tp = tok + (size_t)row * 4;
    float t0 = tp[0], t1 = tp[1], t2 = tp[2], t3 = tp[3];
    int b = row / TDIM;
    int x = (int)(t0 * 100.0f);
    int y = (int)(t1 * 100.0f);
    x = min(max(x, 0), 31);
    y = min(max(y, 0), 31);
    int idx = y * 32 + x;                       // y*H + x, H=32
    float* out = g_ArowsF + (size_t)row * KTOP;
    if (lane < 32) {
        float e = t0 * Wemb[lane] + t1 * Wemb[32 + lane] +
                  t2 * Wemb[64 + lane] + t3 * Wemb[96 + lane] + bemb[lane];
        out[lane] = e;
    }
    const float* fb = feat + (size_t)b * CDIM * HWSZ + idx;
    out[32 + lane]      = fb[(size_t)lane * HWSZ];
    out[32 + 64 + lane] = fb[(size_t)(64 + lane) * HWSZ];
}

// ---- A2a: fold recurrent weights ----
__global__ void kA2a(const float* __restrict__ Wih, const float* __restrict__ Whh,
                     const float* __restrict__ Waap) {
    __shared__ float sa0[128], sa1[128];
    int p = blockIdx.x, n = threadIdx.x;
    int r0 = 2 * p, r1 = 2 * p + 1;
    if (n < 128)            sa0[n]        = Waap[r0 * 128 + n];
    else if (n < 256)       sa1[n - 128]  = Waap[r1 * 128 + (n - 128)];
    __syncthreads();
    float acc0 = (r0 < 128) ? Whh[r0 * G4 + n] : 0.0f;
    float acc1 = (r1 < 128) ? Whh[r1 * G4 + n] : 0.0f;
    for (int j = 0; j < 128; ++j) {
        float wi = Wih[(160 + j) * G4 + n];
        acc0 += sa0[j] * wi;
        acc1 += sa1[j] * wi;
    }
    g_wpack[p * G4 + n] = f2bu(acc0) | (f2bu(acc1) << 16);
}

// ---- A2c: bias vectors, c0, Wao, bao ----
__global__ void kA2c(const float* __restrict__ bih, const float* __restrict__ bhh,
                     const float* __restrict__ Wih, const float* __restrict__ Waap,
                     const float* __restrict__ baap, const float* __restrict__ Wout,
                     const float* __restrict__ bout) {
    __shared__ float sb[128];
    int n = threadIdx.x;
    if (n < 128) sb[n] = baap[n];
    __syncthreads();
    g_bias[n] = bih[n] + bhh[n];
    float c0 = 0.0f;
    for (int j = 0; j < 128; ++j) c0 += sb[j] * Wih[(160 + j) * G4 + n];
    g_c0[n] = c0;
    if (n < 256) {
        for (int o = 0; o < 5; ++o) {
            float acc = 0.0f;
            for (int j = 0; j < 128; ++j) acc += Waap[n * 128 + j] * Wout[j * 5 + o];
            g_Wao[n * 5 + o] = acc;
        }
    }
    if (n == 0) {
        for (int o = 0; o < 5; ++o) {
            float acc = bout[o];
            for (int j = 0; j < 128; ++j) acc += sb[j] * Wout[j * 5 + o];
            g_bao[o] = acc;
        }
    }
}

// ---- A2d: p_enc ----
__global__ void kA2d(const float* __restrict__ FH, const float* __restrict__ Wep,
                     const float* __restrict__ bep) {
    __shared__ float sfh[128 * 64];
    int b = blockIdx.x, tid = threadIdx.x;
    for (int i = tid; i < 128 * 64; i += 256) sfh[i] = FH[(size_t)b * 128 * 64 + i];
    __syncthreads();
    int a = tid & 63, sg = tid >> 6;
    float bias = bep[a];
    float acc[16];
#pragma unroll
    for (int i = 0; i < 16; ++i) acc[i] = bias;
    for (int d = 0; d < 128; ++d) {
        float wa = Wep[d * 64 + a];
#pragma unroll
        for (int i = 0; i < 16; ++i) acc[i] += sfh[d * 64 + sg * 16 + i] * wa;
    }
    for (int i = 0; i < 16; ++i)
        g_penc[((size_t)b * 64 + sg * 16 + i) * 64 + a] = acc[i];
}

// ---- B: pre2 = Arows @ W_ih[0:160]; 2 K-passes of 80 regs, 8 rows/block ----
// Fits the default 128-VGPR cap: wcol[80] + racc[8] + temps ~ 105.
__global__ void __launch_bounds__(512) kB(const float* __restrict__ Wih) {
    int n = threadIdx.x;
    int m0 = blockIdx.x * 8;
    float racc[8];
#pragma unroll
    for (int r = 0; r < 8; ++r) racc[r] = 0.0f;
#pragma unroll 1
    for (int pass = 0; pass < 2; ++pass) {
        float wcol[80];
#pragma unroll
        for (int j = 0; j < 80; ++j) wcol[j] = Wih[(pass * 80 + j) * G4 + n];
#pragma unroll
        for (int r = 0; r < 8; ++r) {
            const float4* rp = (const float4*)(g_ArowsF + (size_t)(m0 + r) * KTOP + pass * 80);
            float a0 = 0.f, a1 = 0.f, a2 = 0.f, a3 = 0.f;
#pragma unroll
            for (int q = 0; q < 20; ++q) {
                float4 v = rp[q];
                a0 += wcol[4 * q + 0] * v.x;
                a1 += wcol[4 * q + 1] * v.y;
                a2 += wcol[4 * q + 2] * v.z;
                a3 += wcol[4 * q + 3] * v.w;
            }
            racc[r] += (a0 + a1) + (a2 + a3);
        }
    }
#pragma unroll
    for (int r = 0; r < 8; ++r)
        g_pre2[(size_t)(m0 + r) * G4 + n] = racc[r];
}

// ---- C: sequential recurrence, 1024 threads/block, K-split gate dot ----
// Thread (kh=tid>>9, n=tid&511) holds wreg[64] (K-half kh of gate n): ~100 VGPRs,
// fits the 128-VGPR cap a 1024-thread (16-wave, 4/SIMD) block gets -> no spill.
__global__ void __launch_bounds__(1024) kC(const float* __restrict__ FH,
                                           const float* __restrict__ W2a,
                                           const float* __restrict__ Walpha,
                                           const float* __restrict__ balpha,
                                           const float* __restrict__ bh2a) {
    __shared__ __align__(16) float s_val[256];   // [h(128) | att(128)]
    __shared__ float s_c[128];
    __shared__ float s_scratch[1024];            // dot partials / gates / reduction scratch
    __shared__ float s_atth[64];
    __shared__ float s_scores[64];
    __shared__ float s_wgt[64];
    __shared__ float s_walpha[64];
    __shared__ float s_bh2a[64];
    __shared__ float s_penc[64 * 65];            // padded stride 65
    __shared__ bf16  s_encp[128 * 70];           // enc[d][s], padded stride 70
    __shared__ bf16  s_w2a[128 * 64];

    int tid = threadIdx.x;
    int b = blockIdx.x;
    int kh = tid >> 9;            // K-half (0/1)
    int n  = tid & 511;           // gate output

    unsigned int wreg[64];
#pragma unroll
    for (int j = 0; j < 64; ++j) wreg[j] = g_wpack[(kh * 64 + j) * G4 + n];

    float bias_r = g_bias[n];     // only meaningful for tid<512 users
    float c0_r   = g_c0[n];

    if (tid < 256) s_val[tid] = 0.0f;
    if (tid < 128) s_c[tid] = 0.0f;
    if (tid < 64) { s_walpha[tid] = Walpha[tid]; s_bh2a[tid] = bh2a[tid]; }
    for (int i = tid; i < 64 * 64; i += 1024) {
        int s = i >> 6, a = i & 63;
        s_penc[s * 65 + a] = g_penc[((size_t)b * 64 + s) * 64 + a];
    }
    for (int i = tid; i < 128 * 64; i += 1024) {
        int d = i >> 6, s = i & 63;
        s_encp[d * 70 + s] = __float2bfloat16(FH[(size_t)b * 128 * 64 + i]);
        s_w2a[i] = __float2bfloat16(W2a[i]);
    }
    float bal = balpha[0];

    const float* pre2p = g_pre2 + (size_t)b * TDIM * G4 + n;
    float* hattp = g_hatt + (size_t)b * TDIM * 256;

    for (int t = 0; t < TDIM; ++t) {
        __syncthreads();                       // s_val (h_{t-1}, att_{t-1}) ready
        float pre2v = (tid < 512) ? pre2p[(size_t)t * G4] : 0.0f;  // issue early
        // gate dot, K-half kh
        float acc0 = 0.f, acc1 = 0.f;
        const float4* vals = (const float4*)(s_val + kh * 128);
#pragma unroll
        for (int q = 0; q < 32; ++q) {
            float4 v = vals[q];
            unsigned int w0 = wreg[2 * q], w1 = wreg[2 * q + 1];
            acc0 += __uint_as_float(w0 << 16)          * v.x;
            acc1 += __uint_as_float(w0 & 0xffff0000u)  * v.y;
            acc0 += __uint_as_float(w1 << 16)          * v.z;
            acc1 += __uint_as_float(w1 & 0xffff0000u)  * v.w;
        }
        s_scratch[tid] = acc0 + acc1;
        __syncthreads();
        if (tid < 512) {
            float g = s_scratch[tid] + s_scratch[tid + 512] + pre2v + bias_r
                      + (t ? c0_r : 0.0f);
            s_scratch[tid] = g;                // each slot read+written by same thread only
        }
        __syncthreads();
        // LSTM pointwise (gate order i,f,g,o)
        if (tid < 128) {
            float si = sigm(s_scratch[tid]);
            float sf = sigm(s_scratch[128 + tid]);
            float tg = tanh_fast(s_scratch[256 + tid]);
            float so = sigm(s_scratch[384 + tid]);
            float c = sf * s_c[tid] + si * tg;
            s_c[tid] = c;
            float h = so * tanh_fast(c);
            s_val[tid] = h;
            hattp[(size_t)t * 256 + tid] = h;
        }
        __syncthreads();
        // att_h = h @ W_h2att  (16 sub-groups of 8 k each)
        {
            int a = tid & 63, sub = tid >> 6;
            float acc = 0.f;
#pragma unroll
            for (int j = 0; j < 8; ++j) {
                int k = sub * 8 + j;
                acc += s_val[k] * b2f(s_w2a[k * 64 + a]);
            }
            s_scratch[sub * 64 + a] = acc;
        }
        __syncthreads();
        if (tid < 64) {
            float acc = s_bh2a[tid];
#pragma unroll
            for (int sub = 0; sub < 16; ++sub) acc += s_scratch[sub * 64 + tid];
            s_atth[tid] = acc;
        }
        __syncthreads();
        // scores[s] = sum_a tanh(p_enc + att_h) * W_alpha   (16 lanes per s, 4 a each)
        {
            int ss = tid >> 4, sub = tid & 15;
            float acc = 0.f;
#pragma unroll
            for (int j = 0; j < 4; ++j) {
                int a = sub * 4 + j;
                float xv = s_penc[ss * 65 + a] + s_atth[a];
                acc += tanh_fast(xv) * s_walpha[a];
            }
            acc += __shfl_xor(acc, 1);
            acc += __shfl_xor(acc, 2);
            acc += __shfl_xor(acc, 4);
            acc += __shfl_xor(acc, 8);
            if (sub == 0) s_scores[ss] = acc + bal;
        }
        __syncthreads();
        if (tid < 64) {
            float v = s_scores[tid];
            float m = v;
#pragma unroll
            for (int off = 32; off > 0; off >>= 1) m = fmaxf(m, __shfl_xor(m, off));
            float e = __expf(v - m);
            float sum = e;
#pragma unroll
            for (int off = 32; off > 0; off >>= 1) sum += __shfl_xor(sum, off);
            s_wgt[tid] = e / sum;
        }
        __syncthreads();
        // att_res[d] = sum_s wgt[s] * enc[s,d]   (8 groups of 8 s each)
        {
            int d = tid & 127, sc = tid >> 7;
            float acc = 0.f;
#pragma unroll
            for (int j = 0; j < 8; ++j) {
                int s5 = sc * 8 + j;
                acc += s_wgt[s5] * b2f(s_encp[d * 70 + s5]);
            }
            s_scratch[sc * 128 + d] = acc;
        }
        __syncthreads();
        if (tid < 128) {
            float att = 0.f;
#pragma unroll
            for (int sc = 0; sc < 8; ++sc) att += s_scratch[sc * 128 + tid];
            s_val[128 + tid] = att;
            hattp[(size_t)t * 256 + 128 + tid] = att;
        }
        // loop-top barrier covers s_val reuse
    }
}

// ---- D: final out = [h|att] @ (W_aap@W_out) + bao, f32 output ----
__global__ void kD(float* __restrict__ out) {
    int r = blockIdx.x, lane = threadIdx.x;
    const float4* hv = (const float4*)(g_hatt + (size_t)r * 256);
    float4 v = hv[lane];
    int k0 = lane * 4;
    float acc[5];
#pragma unroll
    for (int o = 0; o < 5; ++o)
        acc[o] = v.x * g_Wao[(k0 + 0) * 5 + o] + v.y * g_Wao[(k0 + 1) * 5 + o] +
                 v.z * g_Wao[(k0 + 2) * 5 + o] + v.w * g_Wao[(k0 + 3) * 5 + o];
#pragma unroll
    for (int off = 32; off > 0; off >>= 1) {
#pragma unroll
        for (int o = 0; o < 5; ++o) acc[o] += __shfl_xor(acc[o], off);
    }
    if (lane == 0) {
#pragma unroll
        for (int o = 0; o < 5; ++o) out[(size_t)r * 5 + o] = acc[o] + g_bao[o];
    }
}

extern "C" void kernel_launch(void* const* d_in, const int* in_sizes, int n_in,
                              void* d_out, int out_size, void* d_ws, size_t ws_size,
                              hipStream_t stream) {
    (void)in_sizes; (void)n_in; (void)d_ws; (void)ws_size; (void)out_size;
    const float* tok  = (const float*)d_in[0];
    const float* feat = (const float*)d_in[1];
    const float* FH   = (const float*)d_in[2];
    const float* Wemb = (const float*)d_in[3];
    const float* bemb = (const float*)d_in[4];
    const float* Wih  = (const float*)d_in[5];
    const float* bih  = (const float*)d_in[6];
    const float* Whh  = (const float*)d_in[7];
    const float* bhh  = (const float*)d_in[8];
    const float* W2a  = (const float*)d_in[9];
    const float* bh2a = (const float*)d_in[10];
    const float* Wal  = (const float*)d_in[11];
    const float* bal  = (const float*)d_in[12];
    const float* Wep  = (const float*)d_in[13];
    const float* bep  = (const float*)d_in[14];
    const float* Waap = (const float*)d_in[15];
    const float* baap = (const float*)d_in[16];
    const float* Wout = (const float*)d_in[17];
    const float* bout = (const float*)d_in[18];
    float* out = (float*)d_out;

    kA1<<<dim3(BT / 4), dim3(256), 0, stream>>>(tok, feat, Wemb, bemb);
    kA2a<<<dim3(128), dim3(512), 0, stream>>>(Wih, Whh, Waap);
    kA2c<<<dim3(1), dim3(512), 0, stream>>>(bih, bhh, Wih, Waap, baap, Wout, bout);
    kA2d<<<dim3(64), dim3(256), 0, stream>>>(FH, Wep, bep);
    kB<<<dim3(BT / 8), dim3(512), 0, stream>>>(Wih);
    kC<<<dim3(64), dim3(1024), 0, stream>>>(FH, W2a, Wal, bal, bh2a);
    kD<<<dim3(BT), dim3(64), 0, stream>>>(out);
}

// Round 5
// 3526.569 us; speedup vs baseline: 8.8051x; 1.0277x over previous
//
#include <hip/hip_runtime.h>
#include <hip/hip_bf16.h>

#define BDIM 64
#define TDIM 360
#define BT (BDIM*TDIM)        // 23040
#define CDIM 128
#define HWSZ 1024
#define SDIM 64
#define G4 512
#define KTOP 160

typedef __hip_bfloat16 bf16;

static __device__ __forceinline__ unsigned int f2bu(float x) {
    bf16 b = __float2bfloat16(x);
    unsigned short u; __builtin_memcpy(&u, &b, 2); return (unsigned int)u;
}
static __device__ __forceinline__ float b2f(bf16 x) { return __bfloat162float(x); }
static __device__ __forceinline__ float tanh_fast(float x) {
    float e = __expf(2.0f * x);
    return 1.0f - 2.0f / (e + 1.0f);
}
static __device__ __forceinline__ float sigm(float x) {
    return 1.0f / (1.0f + __expf(-x));
}

// ---- static device workspace (~87 MB) ----
__device__ float        g_ArowsF[BT * KTOP];   // [x_emb(32) | in_seq(128)] fp32
__device__ float        g_pre2[BT * G4];       // precomputed non-recurrent gate part
__device__ unsigned int g_wpack[128 * G4];     // folded recurrent weights, bf16 pairs
__device__ float        g_penc[BDIM * SDIM * 64];
__device__ float        g_hatt[BT * 256];      // [h(128) | att(128)] per (b,t)
__device__ float        g_Wao[256 * 5];
__device__ float        g_bao[5];
__device__ float        g_bias[G4];
__device__ float        g_c0[G4];

// ---- A1: build [x_emb | gathered feature] rows (f32 in, f32 out) ----
__global__ void kA1(const float* __restrict__ tok, const float* __restrict__ feat,
                    const float* __restrict__ Wemb, const float* __restrict__ bemb) {
    int row  = blockIdx.x * 4 + (threadIdx.x >> 6);
    int lane = threadIdx.x & 63;
    const float* tp = tok + (size_t)row * 4;
    float t0 = tp[0], t1 = tp[1], t2 = tp[2], t3 = tp[3];
    int b = row / TDIM;
    int x = (int)(t0 * 100.0f);
    int y = (int)(t1 * 100.0f);
    x = min(max(x, 0), 31);
    y = min(max(y, 0), 31);
    int idx = y * 32 + x;                       // y*H + x, H=32
    float* out = g_ArowsF + (size_t)row * KTOP;
    if (lane < 32) {
        float e = t0 * Wemb[lane] + t1 * Wemb[32 + lane] +
                  t2 * Wemb[64 + lane] + t3 * Wemb[96 + lane] + bemb[lane];
        out[lane] = e;
    }
    const float* fb = feat + (size_t)b * CDIM * HWSZ + idx;
    out[32 + lane]      = fb[(size_t)lane * HWSZ];
    out[32 + 64 + lane] = fb[(size_t)(64 + lane) * HWSZ];
}

// ---- A2a: fold recurrent weights ----
__global__ void kA2a(const float* __restrict__ Wih, const float* __restrict__ Whh,
                     const float* __restrict__ Waap) {
    __shared__ float sa0[128], sa1[128];
    int p = blockIdx.x, n = threadIdx.x;
    int r0 = 2 * p, r1 = 2 * p + 1;
    if (n < 128)            sa0[n]        = Waap[r0 * 128 + n];
    else if (n < 256)       sa1[n - 128]  = Waap[r1 * 128 + (n - 128)];
    __syncthreads();
    float acc0 = (r0 < 128) ? Whh[r0 * G4 + n] : 0.0f;
    float acc1 = (r1 < 128) ? Whh[r1 * G4 + n] : 0.0f;
    for (int j = 0; j < 128; ++j) {
        float wi = Wih[(160 + j) * G4 + n];
        acc0 += sa0[j] * wi;
        acc1 += sa1[j] * wi;
    }
    g_wpack[p * G4 + n] = f2bu(acc0) | (f2bu(acc1) << 16);
}

// ---- A2c: bias vectors, c0, Wao, bao ----
__global__ void kA2c(const float* __restrict__ bih, const float* __restrict__ bhh,
                     const float* __restrict__ Wih, const float* __restrict__ Waap,
                     const float* __restrict__ baap, const float* __restrict__ Wout,
                     const float* __restrict__ bout) {
    __shared__ float sb[128];
    int n = threadIdx.x;
    if (n < 128) sb[n] = baap[n];
    __syncthreads();
    g_bias[n] = bih[n] + bhh[n];
    float c0 = 0.0f;
    for (int j = 0; j < 128; ++j) c0 += sb[j] * Wih[(160 + j) * G4 + n];
    g_c0[n] = c0;
    if (n < 256) {
        for (int o = 0; o < 5; ++o) {
            float acc = 0.0f;
            for (int j = 0; j < 128; ++j) acc += Waap[n * 128 + j] * Wout[j * 5 + o];
            g_Wao[n * 5 + o] = acc;
        }
    }
    if (n == 0) {
        for (int o = 0; o < 5; ++o) {
            float acc = bout[o];
            for (int j = 0; j < 128; ++j) acc += sb[j] * Wout[j * 5 + o];
            g_bao[o] = acc;
        }
    }
}

// ---- A2d: p_enc ----
__global__ void kA2d(const float* __restrict__ FH, const float* __restrict__ Wep,
                     const float* __restrict__ bep) {
    __shared__ float sfh[128 * 64];
    int b = blockIdx.x, tid = threadIdx.x;
    for (int i = tid; i < 128 * 64; i += 256) sfh[i] = FH[(size_t)b * 128 * 64 + i];
    __syncthreads();
    int a = tid & 63, sg = tid >> 6;
    float bias = bep[a];
    float acc[16];
#pragma unroll
    for (int i = 0; i < 16; ++i) acc[i] = bias;
    for (int d = 0; d < 128; ++d) {
        float wa = Wep[d * 64 + a];
#pragma unroll
        for (int i = 0; i < 16; ++i) acc[i] += sfh[d * 64 + sg * 16 + i] * wa;
    }
    for (int i = 0; i < 16; ++i)
        g_penc[((size_t)b * 64 + sg * 16 + i) * 64 + a] = acc[i];
}

// ---- B: pre2 = Arows @ W_ih[0:160]; 2 K-passes of 80 regs, 8 rows/block ----
// waves_per_eu(2,2): 256-VGPR budget so wcol[80]+racc[8] stay resident; stops
// the allocator's occupancy-chasing (round-4 lesson: it remats/spills otherwise).
__global__ void __attribute__((amdgpu_flat_work_group_size(512, 512),
                               amdgpu_waves_per_eu(2, 2)))
kB(const float* __restrict__ Wih) {
    int n = threadIdx.x;
    int m0 = blockIdx.x * 8;
    float racc[8];
#pragma unroll
    for (int r = 0; r < 8; ++r) racc[r] = 0.0f;
#pragma unroll 1
    for (int pass = 0; pass < 2; ++pass) {
        float wcol[80];
#pragma unroll
        for (int j = 0; j < 80; ++j) wcol[j] = Wih[(pass * 80 + j) * G4 + n];
#pragma unroll
        for (int r = 0; r < 8; ++r) {
            const float4* rp = (const float4*)(g_ArowsF + (size_t)(m0 + r) * KTOP + pass * 80);
            float a0 = 0.f, a1 = 0.f, a2 = 0.f, a3 = 0.f;
#pragma unroll
            for (int q = 0; q < 20; ++q) {
                float4 v = rp[q];
                a0 += wcol[4 * q + 0] * v.x;
                a1 += wcol[4 * q + 1] * v.y;
                a2 += wcol[4 * q + 2] * v.z;
                a3 += wcol[4 * q + 3] * v.w;
            }
            racc[r] += (a0 + a1) + (a2 + a3);
        }
    }
#pragma unroll
    for (int r = 0; r < 8; ++r)
        g_pre2[(size_t)(m0 + r) * G4 + n] = racc[r];
}

// ---- C: sequential recurrence, 1024 threads/block, K-split gate dot ----
// ONE block per CU (64 blocks) = 16 waves = exactly 4 waves/EU. waves_per_eu(4,4)
// caps the allocator's occupancy target at what we actually run, giving a
// 128-VGPR budget so wreg[64] (~105 total) is register-resident.
// Round-4 counter evidence: default alloc crushed to 64 VGPRs and re-loaded
// all weights from L2 every step (VALUBusy 3.9%, 9 us/step).
__global__ void __attribute__((amdgpu_flat_work_group_size(1024, 1024),
                               amdgpu_waves_per_eu(4, 4)))
kC(const float* __restrict__ FH,
   const float* __restrict__ W2a,
   const float* __restrict__ Walpha,
   const float* __restrict__ balpha,
   const float* __restrict__ bh2a) {
    __shared__ __align__(16) float s_val[256];   // [h(128) | att(128)]
    __shared__ float s_c[128];
    __shared__ float s_scratch[1024];            // dot partials / gates / reduction scratch
    __shared__ float s_atth[64];
    __shared__ float s_scores[64];
    __shared__ float s_wgt[64];
    __shared__ float s_walpha[64];
    __shared__ float s_bh2a[64];
    __shared__ float s_penc[64 * 65];            // padded stride 65
    __shared__ bf16  s_encp[128 * 70];           // enc[d][s], padded stride 70
    __shared__ bf16  s_w2a[128 * 64];

    int tid = threadIdx.x;
    int b = blockIdx.x;
    int kh = tid >> 9;            // K-half (0/1)
    int n  = tid & 511;           // gate output

    unsigned int wreg[64];
#pragma unroll
    for (int j = 0; j < 64; ++j) wreg[j] = g_wpack[(kh * 64 + j) * G4 + n];

    float bias_r = g_bias[n];     // only meaningful for tid<512 users
    float c0_r   = g_c0[n];

    if (tid < 256) s_val[tid] = 0.0f;
    if (tid < 128) s_c[tid] = 0.0f;
    if (tid < 64) { s_walpha[tid] = Walpha[tid]; s_bh2a[tid] = bh2a[tid]; }
    for (int i = tid; i < 64 * 64; i += 1024) {
        int s = i >> 6, a = i & 63;
        s_penc[s * 65 + a] = g_penc[((size_t)b * 64 + s) * 64 + a];
    }
    for (int i = tid; i < 128 * 64; i += 1024) {
        int d = i >> 6, s = i & 63;
        s_encp[d * 70 + s] = __float2bfloat16(FH[(size_t)b * 128 * 64 + i]);
        s_w2a[i] = __float2bfloat16(W2a[i]);
    }
    float bal = balpha[0];

    const float* pre2p = g_pre2 + (size_t)b * TDIM * G4 + n;
    float* hattp = g_hatt + (size_t)b * TDIM * 256;

    for (int t = 0; t < TDIM; ++t) {
        __syncthreads();                       // s_val (h_{t-1}, att_{t-1}) ready
        float pre2v = (tid < 512) ? pre2p[(size_t)t * G4] : 0.0f;  // issue early
        // gate dot, K-half kh
        float acc0 = 0.f, acc1 = 0.f;
        const float4* vals = (const float4*)(s_val + kh * 128);
#pragma unroll
        for (int q = 0; q < 32; ++q) {
            float4 v = vals[q];
            unsigned int w0 = wreg[2 * q], w1 = wreg[2 * q + 1];
            acc0 += __uint_as_float(w0 << 16)          * v.x;
            acc1 += __uint_as_float(w0 & 0xffff0000u)  * v.y;
            acc0 += __uint_as_float(w1 << 16)          * v.z;
            acc1 += __uint_as_float(w1 & 0xffff0000u)  * v.w;
        }
        s_scratch[tid] = acc0 + acc1;
        __syncthreads();
        if (tid < 512) {
            float g = s_scratch[tid] + s_scratch[tid + 512] + pre2v + bias_r
                      + (t ? c0_r : 0.0f);
            s_scratch[tid] = g;                // each slot read+written by same thread only
        }
        __syncthreads();
        // LSTM pointwise (gate order i,f,g,o)
        if (tid < 128) {
            float si = sigm(s_scratch[tid]);
            float sf = sigm(s_scratch[128 + tid]);
            float tg = tanh_fast(s_scratch[256 + tid]);
            float so = sigm(s_scratch[384 + tid]);
            float c = sf * s_c[tid] + si * tg;
            s_c[tid] = c;
            float h = so * tanh_fast(c);
            s_val[tid] = h;
            hattp[(size_t)t * 256 + tid] = h;
        }
        __syncthreads();
        // att_h = h @ W_h2att  (16 sub-groups of 8 k each)
        {
            int a = tid & 63, sub = tid >> 6;
            float acc = 0.f;
#pragma unroll
            for (int j = 0; j < 8; ++j) {
                int k = sub * 8 + j;
                acc += s_val[k] * b2f(s_w2a[k * 64 + a]);
            }
            s_scratch[sub * 64 + a] = acc;
        }
        __syncthreads();
        if (tid < 64) {
            float acc = s_bh2a[tid];
#pragma unroll
            for (int sub = 0; sub < 16; ++sub) acc += s_scratch[sub * 64 + tid];
            s_atth[tid] = acc;
        }
        __syncthreads();
        // scores[s] = sum_a tanh(p_enc + att_h) * W_alpha   (16 lanes per s, 4 a each)
        {
            int ss = tid >> 4, sub = tid & 15;
            float acc = 0.f;
#pragma unroll
            for (int j = 0; j < 4; ++j) {
                int a = sub * 4 + j;
                float xv = s_penc[ss * 65 + a] + s_atth[a];
                acc += tanh_fast(xv) * s_walpha[a];
            }
            acc += __shfl_xor(acc, 1);
            acc += __shfl_xor(acc, 2);
            acc += __shfl_xor(acc, 4);
            acc += __shfl_xor(acc, 8);
            if (sub == 0) s_scores[ss] = acc + bal;
        }
        __syncthreads();
        if (tid < 64) {
            float v = s_scores[tid];
            float m = v;
#pragma unroll
            for (int off = 32; off > 0; off >>= 1) m = fmaxf(m, __shfl_xor(m, off));
            float e = __expf(v - m);
            float sum = e;
#pragma unroll
            for (int off = 32; off > 0; off >>= 1) sum += __shfl_xor(sum, off);
            s_wgt[tid] = e / sum;
        }
        __syncthreads();
        // att_res[d] = sum_s wgt[s] * enc[s,d]   (8 groups of 8 s each)
        {
            int d = tid & 127, sc = tid >> 7;
            float acc = 0.f;
#pragma unroll
            for (int j = 0; j < 8; ++j) {
                int s5 = sc * 8 + j;
                acc += s_wgt[s5] * b2f(s_encp[d * 70 + s5]);
            }
            s_scratch[sc * 128 + d] = acc;
        }
        __syncthreads();
        if (tid < 128) {
            float att = 0.f;
#pragma unroll
            for (int sc = 0; sc < 8; ++sc) att += s_scratch[sc * 128 + tid];
            s_val[128 + tid] = att;
            hattp[(size_t)t * 256 + 128 + tid] = att;
        }
        // loop-top barrier covers s_val reuse
    }
}

// ---- D: final out = [h|att] @ (W_aap@W_out) + bao, f32 output ----
__global__ void kD(float* __restrict__ out) {
    int r = blockIdx.x, lane = threadIdx.x;
    const float4* hv = (const float4*)(g_hatt + (size_t)r * 256);
    float4 v = hv[lane];
    int k0 = lane * 4;
    float acc[5];
#pragma unroll
    for (int o = 0; o < 5; ++o)
        acc[o] = v.x * g_Wao[(k0 + 0) * 5 + o] + v.y * g_Wao[(k0 + 1) * 5 + o] +
                 v.z * g_Wao[(k0 + 2) * 5 + o] + v.w * g_Wao[(k0 + 3) * 5 + o];
#pragma unroll
    for (int off = 32; off > 0; off >>= 1) {
#pragma unroll
        for (int o = 0; o < 5; ++o) acc[o] += __shfl_xor(acc[o], off);
    }
    if (lane == 0) {
#pragma unroll
        for (int o = 0; o < 5; ++o) out[(size_t)r * 5 + o] = acc[o] + g_bao[o];
    }
}

extern "C" void kernel_launch(void* const* d_in, const int* in_sizes, int n_in,
                              void* d_out, int out_size, void* d_ws, size_t ws_size,
                              hipStream_t stream) {
    (void)in_sizes; (void)n_in; (void)d_ws; (void)ws_size; (void)out_size;
    const float* tok  = (const float*)d_in[0];
    const float* feat = (const float*)d_in[1];
    const float* FH   = (const float*)d_in[2];
    const float* Wemb = (const float*)d_in[3];
    const float* bemb = (const float*)d_in[4];
    const float* Wih  = (const float*)d_in[5];
    const float* bih  = (const float*)d_in[6];
    const float* Whh  = (const float*)d_in[7];
    const float* bhh  = (const float*)d_in[8];
    const float* W2a  = (const float*)d_in[9];
    const float* bh2a = (const float*)d_in[10];
    const float* Wal  = (const float*)d_in[11];
    const float* bal  = (const float*)d_in[12];
    const float* Wep  = (const float*)d_in[13];
    const float* bep  = (const float*)d_in[14];
    const float* Waap = (const float*)d_in[15];
    const float* baap = (const float*)d_in[16];
    const float* Wout = (const float*)d_in[17];
    const float* bout = (const float*)d_in[18];
    float* out = (float*)d_out;

    kA1<<<dim3(BT / 4), dim3(256), 0, stream>>>(tok, feat, Wemb, bemb);
    kA2a<<<dim3(128), dim3(512), 0, stream>>>(Wih, Whh, Waap);
    kA2c<<<dim3(1), dim3(512), 0, stream>>>(bih, bhh, Wih, Waap, baap, Wout, bout);
    kA2d<<<dim3(64), dim3(256), 0, stream>>>(FH, Wep, bep);
    kB<<<dim3(BT / 8), dim3(512), 0, stream>>>(Wih);
    kC<<<dim3(64), dim3(1024), 0, stream>>>(FH, W2a, Wal, bal, bh2a);
    kD<<<dim3(BT), dim3(64), 0, stream>>>(out);
}